// Round 11
// baseline (267.610 us; speedup 1.0000x reference)
//
#include <hip/hip_runtime.h>
#include <stdint.h>

// out[index[i]] += value[i], duplicates accumulate. N = 2^24 table, M = 2^25 updates.
// Counting sort, no global atomics (capped ~26 G/s on gfx950, rounds 1-3).
// Round-11: ip_bin restructured as 4 sub-chunks of 4096 per block with a
// persistent LDS cursor gcur[] -> staging LDS 52.5KB -> 32.8KB, 2 -> 4
// blocks/CU (bin was latency-bound: 2.9 TB/s, VALUBusy 15%, occ 52%).
// gcnt granularity 16384 (8 MB). XCD-chunked swizzles retained (round 8).

#define LOGSLICE  14
#define SLICE     (1 << LOGSLICE)     // 16384 table entries per bucket (64 KiB acc)
#define NB        1024                // buckets = 2^24 / 2^14
#define CHUNK     16384               // updates per count/bin block
#define SUB       4096                // updates per bin sub-chunk (LDS staging unit)
#define NSUB      (CHUNK / SUB)       // 4
#define CNT_THR   256
#define BIN_THR   512

typedef int      v4i __attribute__((ext_vector_type(4)));
typedef uint32_t v4u __attribute__((ext_vector_type(4)));

#define NTL(x)    __builtin_nontemporal_load(&(x))
#define NTS(p, v) __builtin_nontemporal_store((v), &(p))

// ---------- K1: per-chunk bucket histogram ----------
__global__ __launch_bounds__(256) void ip_count(const v4u* __restrict__ index4,
                                                uint32_t* __restrict__ gcnt) {
    __shared__ uint32_t cnt[NB];
    const int t = threadIdx.x, c = blockIdx.x;
    for (int i = t; i < NB; i += CNT_THR) cnt[i] = 0;
    __syncthreads();
    const int base4 = c * (CHUNK / 4);
#pragma unroll
    for (int k = 0; k < CHUNK / 4 / CNT_THR; ++k) {
        v4u id = NTL(index4[base4 + t + k * CNT_THR]);
        atomicAdd(&cnt[id[0] >> LOGSLICE], 1u);
        atomicAdd(&cnt[id[1] >> LOGSLICE], 1u);
        atomicAdd(&cnt[id[2] >> LOGSLICE], 1u);
        atomicAdd(&cnt[id[3] >> LOGSLICE], 1u);
    }
    __syncthreads();
    for (int i = t; i < NB; i += CNT_THR)
        gcnt[(size_t)c * NB + i] = cnt[i];
}

// ---------- K2: exclusive scan over chunks, per bucket ----------
#define SC_THR  256
#define SC_EPT  8         // chunks per thread (B must equal SC_THR*SC_EPT = 2048)
__global__ __launch_bounds__(256) void ip_scan_chunks(uint32_t* __restrict__ gcnt,
                                                      uint32_t* __restrict__ btotal) {
    __shared__ uint32_t wsum[SC_THR / 64];
    const int t = threadIdx.x;
    const int b = (int)((blockIdx.x & 7) * (gridDim.x >> 3) + (blockIdx.x >> 3));
    const int lane = t & 63, w = t >> 6;

    uint32_t v[SC_EPT];
#pragma unroll
    for (int k = 0; k < SC_EPT; ++k)
        v[k] = gcnt[(size_t)(t * SC_EPT + k) * NB + b];
    uint32_t s = 0;
#pragma unroll
    for (int k = 0; k < SC_EPT; ++k) { uint32_t x = v[k]; v[k] = s; s += x; }

    uint32_t incl = s;
#pragma unroll
    for (int off = 1; off < 64; off <<= 1) {
        uint32_t u = __shfl_up(incl, off);
        if (lane >= off) incl += u;
    }
    if (lane == 63) wsum[w] = incl;
    __syncthreads();
    uint32_t woff = 0;
    for (int i = 0; i < w; ++i) woff += wsum[i];
    const uint32_t base = woff + incl - s;

#pragma unroll
    for (int k = 0; k < SC_EPT; ++k)
        gcnt[(size_t)(t * SC_EPT + k) * NB + b] = base + v[k];

    if (t == SC_THR - 1) btotal[b] = base + s;
}

// ---------- K3: exclusive scan over buckets ----------
__global__ __launch_bounds__(1024) void ip_scan_buckets(const uint32_t* __restrict__ btotal,
                                                        uint32_t* __restrict__ bbase) {
    __shared__ uint32_t tmp[NB];
    const int t = threadIdx.x;
    uint32_t v = btotal[t];
    tmp[t] = v; __syncthreads();
    for (int off = 1; off < NB; off <<= 1) {
        uint32_t u = (t >= off) ? tmp[t - off] : 0; __syncthreads();
        tmp[t] += u; __syncthreads();
    }
    bbase[t] = tmp[t] - v;
}

// ---------- K4: bin, 4 sub-chunks of 4096 with persistent LDS cursors ----------
__global__ __launch_bounds__(512) void ip_bin(const v4u* __restrict__ index4,
                                              const v4u* __restrict__ value4,
                                              const uint32_t* __restrict__ gcnt,
                                              const uint32_t* __restrict__ bbase,
                                              uint32_t* __restrict__ pairs) {
    __shared__ uint32_t gcur[NB];       // persistent global cursor per bucket
    __shared__ uint32_t lst[NB];        // per-sub-chunk: counts -> lstart -> doff
    __shared__ uint32_t spk[SUB];       // staged payload, bucket-grouped (16 KiB)
    __shared__ uint16_t sbid[SUB];      // bucket id per staged slot (8 KiB)
    __shared__ uint32_t wsum[BIN_THR / 64];
    const int t = threadIdx.x;
    // XCD-chunked swizzle: consecutive chunks share an XCD L2 -> partial-line
    // run writes merge before writeback (round 8: WRITE 247 -> 145 MB).
    const int c = (int)((blockIdx.x & 7) * (gridDim.x >> 3) + (blockIdx.x >> 3));
    const int lane = t & 63, w = t >> 6;

    // seed cursors (each thread owns buckets 2t, 2t+1 throughout)
    gcur[t * 2 + 0] = bbase[t * 2 + 0] + gcnt[(size_t)c * NB + t * 2 + 0];
    gcur[t * 2 + 1] = bbase[t * 2 + 1] + gcnt[(size_t)c * NB + t * 2 + 1];

    const int cbase4 = c * (CHUNK / 4);
#pragma unroll 1
    for (int s = 0; s < NSUB; ++s) {
        // 1. zero counts
        lst[t * 2 + 0] = 0;
        lst[t * 2 + 1] = 0;
        __syncthreads();

        // 2. load sub-chunk + count with returned rank
        v4u idx[2], val[2];
#pragma unroll
        for (int k = 0; k < 2; ++k) {
            idx[k] = NTL(index4[cbase4 + s * (SUB / 4) + t + k * BIN_THR]);
            val[k] = NTL(value4[cbase4 + s * (SUB / 4) + t + k * BIN_THR]);
        }
        uint32_t lrank[8];
#pragma unroll
        for (int k = 0; k < 2; ++k) {
            lrank[k * 4 + 0] = atomicAdd(&lst[idx[k][0] >> LOGSLICE], 1u);
            lrank[k * 4 + 1] = atomicAdd(&lst[idx[k][1] >> LOGSLICE], 1u);
            lrank[k * 4 + 2] = atomicAdd(&lst[idx[k][2] >> LOGSLICE], 1u);
            lrank[k * 4 + 3] = atomicAdd(&lst[idx[k][3] >> LOGSLICE], 1u);
        }
        __syncthreads();

        // 3. exclusive scan counts -> lstart (wave shfl + cross-wave)
        uint32_t c0 = lst[t * 2 + 0], c1 = lst[t * 2 + 1];
        uint32_t sum = c0 + c1;
        uint32_t incl = sum;
#pragma unroll
        for (int off = 1; off < 64; off <<= 1) {
            uint32_t u = __shfl_up(incl, off);
            if (lane >= off) incl += u;
        }
        if (lane == 63) wsum[w] = incl;
        __syncthreads();
        uint32_t woff = 0;
        for (int i = 0; i < w; ++i) woff += wsum[i];
        uint32_t ex = woff + incl - sum;
        lst[t * 2 + 0] = ex;
        lst[t * 2 + 1] = ex + c0;
        __syncthreads();

        // 4. place into LDS, grouped by bucket
#pragma unroll
        for (int k = 0; k < 2; ++k)
#pragma unroll
            for (int e = 0; e < 4; ++e) {
                uint32_t ix = idx[k][e];
                uint32_t b_ = ix >> LOGSLICE;
                uint32_t p_ = lst[b_] + lrank[k * 4 + e];
                spk[p_]  = (val[k][e] << LOGSLICE) | (ix & (SLICE - 1));
                sbid[p_] = (uint16_t)b_;
            }
        __syncthreads();

        // 5. lst[b] := doff[b] = gcur[b] - lstart[b]   (own entries only)
        lst[t * 2 + 0] = gcur[t * 2 + 0] - lst[t * 2 + 0];
        lst[t * 2 + 1] = gcur[t * 2 + 1] - lst[t * 2 + 1];
        __syncthreads();

        // 6. write out: consecutive j in a bucket -> consecutive global addrs
#pragma unroll
        for (int k = 0; k < SUB / BIN_THR; ++k) {
            int j = t + k * BIN_THR;
            uint32_t b_ = sbid[j];
            pairs[lst[b_] + (uint32_t)j] = spk[j];
        }
        __syncthreads();

        // 7. advance cursors (own entries; next use is after 2+ barriers)
        gcur[t * 2 + 0] += c0;
        gcur[t * 2 + 1] += c1;
    }
}

// ---------- K5: per-slice LDS accumulate, out = input + acc ----------
__global__ __launch_bounds__(1024) void ip_accumulate(const uint32_t* __restrict__ pairs,
                                                      const uint32_t* __restrict__ btotal,
                                                      const uint32_t* __restrict__ bbase,
                                                      const v4i* __restrict__ input4,
                                                      v4i* __restrict__ out4) {
    __shared__ uint32_t acc[SLICE];    // 64 KiB
    const int t = threadIdx.x;
    const int b = (int)((blockIdx.x & 7) * (gridDim.x >> 3) + (blockIdx.x >> 3));
    for (int j = t; j < SLICE; j += 1024) acc[j] = 0;
    __syncthreads();

    const uint32_t beg = bbase[b];
    const uint32_t cnt = btotal[b];

    uint32_t head = (4u - (beg & 3u)) & 3u;
    if (head > cnt) head = cnt;
    if (t < (int)head) {
        uint32_t pk = pairs[beg + t];
        atomicAdd(&acc[pk & (SLICE - 1)], pk >> LOGSLICE);
    }
    const uint32_t rem = cnt - head;
    const uint32_t n4  = rem >> 2;
    const uint32_t* __restrict__ p = pairs + beg + head;
    const v4u* __restrict__ p4 = (const v4u*)p;
    for (uint32_t j = t; j < n4; j += 1024) {
        v4u pk = NTL(p4[j]);
        atomicAdd(&acc[pk[0] & (SLICE - 1)], pk[0] >> LOGSLICE);
        atomicAdd(&acc[pk[1] & (SLICE - 1)], pk[1] >> LOGSLICE);
        atomicAdd(&acc[pk[2] & (SLICE - 1)], pk[2] >> LOGSLICE);
        atomicAdd(&acc[pk[3] & (SLICE - 1)], pk[3] >> LOGSLICE);
    }
    for (uint32_t j = (n4 << 2) + t; j < rem; j += 1024) {
        uint32_t pk = p[j];
        atomicAdd(&acc[pk & (SLICE - 1)], pk >> LOGSLICE);
    }
    __syncthreads();

    const int base4 = b * (SLICE / 4);
    for (int j = t; j < SLICE / 4; j += 1024) {
        v4i in = NTL(input4[base4 + j]);
        in[0] += (int)acc[j * 4 + 0];
        in[1] += (int)acc[j * 4 + 1];
        in[2] += (int)acc[j * 4 + 2];
        in[3] += (int)acc[j * 4 + 3];
        NTS(out4[base4 + j], in);
    }
}

// ---------- fallback: direct atomics ----------
__global__ void ip_copy_kernel(const int4* __restrict__ in, int4* __restrict__ out, int n4) {
    int stride = gridDim.x * blockDim.x;
    for (int i = blockIdx.x * blockDim.x + threadIdx.x; i < n4; i += stride)
        out[i] = in[i];
}
__global__ void ip_scatter1_kernel(const int* __restrict__ index, const int* __restrict__ value,
                                   int* __restrict__ out, int m) {
    int stride = gridDim.x * blockDim.x;
    for (int i = blockIdx.x * blockDim.x + threadIdx.x; i < m; i += stride)
        atomicAdd(&out[index[i]], value[i]);
}

extern "C" void kernel_launch(void* const* d_in, const int* in_sizes, int n_in,
                              void* d_out, int out_size, void* d_ws, size_t ws_size,
                              hipStream_t stream) {
    const int* input = (const int*)d_in[0];
    const int* index = (const int*)d_in[1];
    const int* value = (const int*)d_in[2];
    int* out = (int*)d_out;

    const int N = in_sizes[0];
    const int M = in_sizes[1];
    const int B = M / CHUNK;   // chunks (2048)

    const size_t gcnt_bytes = (size_t)B * NB * sizeof(uint32_t);      // 8 MB
    const size_t tot_bytes  = NB * sizeof(uint32_t);
    const size_t need = gcnt_bytes + 2 * tot_bytes + (size_t)M * sizeof(uint32_t);

    const bool ok = (N == NB * SLICE) && (M % CHUNK == 0) && (B == SC_THR * SC_EPT) &&
                    (B % 8 == 0) && (ws_size >= need);

    if (ok) {
        uint32_t* gcnt   = (uint32_t*)d_ws;
        uint32_t* btotal = (uint32_t*)((char*)d_ws + gcnt_bytes);
        uint32_t* bbase  = btotal + NB;
        uint32_t* pairs  = bbase + NB;

        ip_count<<<B, CNT_THR, 0, stream>>>((const v4u*)index, gcnt);
        ip_scan_chunks<<<NB, SC_THR, 0, stream>>>(gcnt, btotal);
        ip_scan_buckets<<<1, NB, 0, stream>>>(btotal, bbase);
        ip_bin<<<B, BIN_THR, 0, stream>>>((const v4u*)index, (const v4u*)value,
                                          gcnt, bbase, pairs);
        ip_accumulate<<<NB, 1024, 0, stream>>>(pairs, btotal, bbase,
                                               (const v4i*)input, (v4i*)out);
    } else {
        ip_copy_kernel<<<2048, 256, 0, stream>>>((const int4*)input, (int4*)d_out, N / 4);
        ip_scatter1_kernel<<<2048, 256, 0, stream>>>(index, value, out, M);
    }
}

// Round 12
// 200.015 us; speedup vs baseline: 1.3379x; 1.3379x over previous
//
#include <hip/hip_runtime.h>
#include <stdint.h>

// out[index[i]] += value[i], duplicates accumulate. N = 2^24 table, M = 2^25 updates.
// Counting sort, no global atomics (capped ~26 G/s on gfx950, rounds 1-3).
// Round-12: round-10 bin structure (CHUNK 8192 -> avg-8 runs, WRITE ~143MB;
// round-11's sub-chunking broke L2 write-merge: 482MB, regressed) with sbid
// DELETED: bucket-id low 8 bits ride in spk's top byte (payload is 24b), high
// 2 bits recovered from j vs lstart[256/512/768] thresholds. Bin LDS 52.5->36KB
// -> 4 blocks/CU (100% occ). accumulate masks the value field with &1023.

#define LOGSLICE  14
#define SLICE     (1 << LOGSLICE)     // 16384 table entries per bucket (64 KiB acc)
#define NB        1024                // buckets = 2^24 / 2^14
#define CHUNK     8192                // updates per count/bin block
#define CNT_THR   256
#define BIN_THR   512
#define EPT       (CHUNK / 4 / BIN_THR)   // int4 loads per thread in bin = 4

typedef int      v4i __attribute__((ext_vector_type(4)));
typedef uint32_t v4u __attribute__((ext_vector_type(4)));

#define NTL(x)    __builtin_nontemporal_load(&(x))
#define NTS(p, v) __builtin_nontemporal_store((v), &(p))

// ---------- K1: per-chunk bucket histogram ----------
__global__ __launch_bounds__(256) void ip_count(const v4u* __restrict__ index4,
                                                uint32_t* __restrict__ gcnt) {
    __shared__ uint32_t cnt[NB];
    const int t = threadIdx.x, c = blockIdx.x;
    for (int i = t; i < NB; i += CNT_THR) cnt[i] = 0;
    __syncthreads();
    const int base4 = c * (CHUNK / 4);
#pragma unroll
    for (int k = 0; k < CHUNK / 4 / CNT_THR; ++k) {
        v4u id = NTL(index4[base4 + t + k * CNT_THR]);
        atomicAdd(&cnt[id[0] >> LOGSLICE], 1u);
        atomicAdd(&cnt[id[1] >> LOGSLICE], 1u);
        atomicAdd(&cnt[id[2] >> LOGSLICE], 1u);
        atomicAdd(&cnt[id[3] >> LOGSLICE], 1u);
    }
    __syncthreads();
    for (int i = t; i < NB; i += CNT_THR)
        gcnt[(size_t)c * NB + i] = cnt[i];
}

// ---------- K2: exclusive scan over chunks, per bucket ----------
#define SC_THR  256
#define SC_EPT  16        // chunks per thread (B must equal SC_THR*SC_EPT = 4096)
__global__ __launch_bounds__(256) void ip_scan_chunks(uint32_t* __restrict__ gcnt,
                                                      uint32_t* __restrict__ btotal) {
    __shared__ uint32_t wsum[SC_THR / 64];
    const int t = threadIdx.x;
    const int b = (int)((blockIdx.x & 7) * (gridDim.x >> 3) + (blockIdx.x >> 3));
    const int lane = t & 63, w = t >> 6;

    uint32_t v[SC_EPT];
#pragma unroll
    for (int k = 0; k < SC_EPT; ++k)
        v[k] = gcnt[(size_t)(t * SC_EPT + k) * NB + b];
    uint32_t s = 0;
#pragma unroll
    for (int k = 0; k < SC_EPT; ++k) { uint32_t x = v[k]; v[k] = s; s += x; }

    uint32_t incl = s;
#pragma unroll
    for (int off = 1; off < 64; off <<= 1) {
        uint32_t u = __shfl_up(incl, off);
        if (lane >= off) incl += u;
    }
    if (lane == 63) wsum[w] = incl;
    __syncthreads();
    uint32_t woff = 0;
    for (int i = 0; i < w; ++i) woff += wsum[i];
    const uint32_t base = woff + incl - s;

#pragma unroll
    for (int k = 0; k < SC_EPT; ++k)
        gcnt[(size_t)(t * SC_EPT + k) * NB + b] = base + v[k];

    if (t == SC_THR - 1) btotal[b] = base + s;
}

// ---------- K3: exclusive scan over buckets ----------
__global__ __launch_bounds__(1024) void ip_scan_buckets(const uint32_t* __restrict__ btotal,
                                                        uint32_t* __restrict__ bbase) {
    __shared__ uint32_t tmp[NB];
    const int t = threadIdx.x;
    uint32_t v = btotal[t];
    tmp[t] = v; __syncthreads();
    for (int off = 1; off < NB; off <<= 1) {
        uint32_t u = (t >= off) ? tmp[t - off] : 0; __syncthreads();
        tmp[t] += u; __syncthreads();
    }
    bbase[t] = tmp[t] - v;
}

// ---------- K4: bin into bucket-contiguous runs via LDS staging ----------
__global__ __launch_bounds__(512) void ip_bin(const v4u* __restrict__ index4,
                                              const v4u* __restrict__ value4,
                                              const uint32_t* __restrict__ gcnt,
                                              const uint32_t* __restrict__ bbase,
                                              uint32_t* __restrict__ pairs) {
    __shared__ uint32_t cur[NB];        // counts -> lstart -> doff (reused in place)
    __shared__ uint32_t spk[CHUNK];     // payload | b_low8<<24, bucket-grouped (32 KiB)
    __shared__ uint32_t wsum[BIN_THR / 64];
    const int t = threadIdx.x;
    // XCD-chunked swizzle: consecutive chunks share an XCD L2 -> adjacent
    // per-bucket run segments merge into full lines before writeback (round 8).
    const int c = (int)((blockIdx.x & 7) * (gridDim.x >> 3) + (blockIdx.x >> 3));
    const int lane = t & 63, w = t >> 6;

    cur[t * 2 + 0] = 0;
    cur[t * 2 + 1] = 0;
    __syncthreads();

    const int base4 = c * (CHUNK / 4);
    v4u idx[EPT], val[EPT];
#pragma unroll
    for (int k = 0; k < EPT; ++k) {
        idx[k] = NTL(index4[base4 + t + k * BIN_THR]);
        val[k] = NTL(value4[base4 + t + k * BIN_THR]);
    }
    uint32_t lrank[EPT * 4];
#pragma unroll
    for (int k = 0; k < EPT; ++k) {
        lrank[k * 4 + 0] = atomicAdd(&cur[idx[k][0] >> LOGSLICE], 1u);
        lrank[k * 4 + 1] = atomicAdd(&cur[idx[k][1] >> LOGSLICE], 1u);
        lrank[k * 4 + 2] = atomicAdd(&cur[idx[k][2] >> LOGSLICE], 1u);
        lrank[k * 4 + 3] = atomicAdd(&cur[idx[k][3] >> LOGSLICE], 1u);
    }
    __syncthreads();

    // exclusive scan of per-bucket counts -> lstart (2 buckets/thread), wave shfl scan
    uint32_t c0 = cur[t * 2 + 0], c1 = cur[t * 2 + 1];
    uint32_t s = c0 + c1;
    uint32_t incl = s;
#pragma unroll
    for (int off = 1; off < 64; off <<= 1) {
        uint32_t u = __shfl_up(incl, off);
        if (lane >= off) incl += u;
    }
    if (lane == 63) wsum[w] = incl;
    __syncthreads();
    uint32_t woff = 0;
    for (int i = 0; i < w; ++i) woff += wsum[i];
    uint32_t ex = woff + incl - s;
    cur[t * 2 + 0] = ex;
    cur[t * 2 + 1] = ex + c0;
    __syncthreads();

    // place: slot = lstart[b] + lrank; bucket-id low8 rides in the top byte
#pragma unroll
    for (int k = 0; k < EPT; ++k)
#pragma unroll
        for (int e = 0; e < 4; ++e) {
            uint32_t ix = idx[k][e];
            uint32_t b_ = ix >> LOGSLICE;
            uint32_t p_ = cur[b_] + lrank[k * 4 + e];
            spk[p_] = (b_ << 24) | (val[k][e] << LOGSLICE) | (ix & (SLICE - 1));
        }
    __syncthreads();

    // snapshot quadrant thresholds while cur still holds lstart
    const uint32_t L256 = cur[256], L512 = cur[512], L768 = cur[768];
    __syncthreads();

    // cur[b] := doff[b] = bbase[b] + chunk_off[b] - lstart[b]  (addr = doff[b] + j)
#pragma unroll
    for (int r = 0; r < 2; ++r) {
        int i = t + r * BIN_THR;
        cur[i] = bbase[i] + gcnt[(size_t)c * NB + i] - cur[i];
    }
    __syncthreads();

    // write out: consecutive j within a bucket -> consecutive global addresses.
    // b = spk_top8 + 256 * (#thresholds <= j)  (bucket(j) is non-decreasing in j)
#pragma unroll
    for (int k = 0; k < CHUNK / BIN_THR; ++k) {
        uint32_t j = (uint32_t)(t + k * BIN_THR);
        uint32_t pk = spk[j];
        uint32_t b_ = (pk >> 24) + ((j >= L256) + (j >= L512) + (j >= L768)) * 256u;
        pairs[cur[b_] + j] = pk;
    }
}

// ---------- K5: per-slice LDS accumulate, out = input + acc ----------
__global__ __launch_bounds__(1024) void ip_accumulate(const uint32_t* __restrict__ pairs,
                                                      const uint32_t* __restrict__ btotal,
                                                      const uint32_t* __restrict__ bbase,
                                                      const v4i* __restrict__ input4,
                                                      v4i* __restrict__ out4) {
    __shared__ uint32_t acc[SLICE];    // 64 KiB
    const int t = threadIdx.x;
    const int b = (int)((blockIdx.x & 7) * (gridDim.x >> 3) + (blockIdx.x >> 3));
    for (int j = t; j < SLICE; j += 1024) acc[j] = 0;
    __syncthreads();

    const uint32_t beg = bbase[b];
    const uint32_t cnt = btotal[b];

    uint32_t head = (4u - (beg & 3u)) & 3u;
    if (head > cnt) head = cnt;
    if (t < (int)head) {
        uint32_t pk = pairs[beg + t];
        atomicAdd(&acc[pk & (SLICE - 1)], (pk >> LOGSLICE) & 1023u);
    }
    const uint32_t rem = cnt - head;
    const uint32_t n4  = rem >> 2;
    const uint32_t* __restrict__ p = pairs + beg + head;
    const v4u* __restrict__ p4 = (const v4u*)p;
    for (uint32_t j = t; j < n4; j += 1024) {
        v4u pk = NTL(p4[j]);
        atomicAdd(&acc[pk[0] & (SLICE - 1)], (pk[0] >> LOGSLICE) & 1023u);
        atomicAdd(&acc[pk[1] & (SLICE - 1)], (pk[1] >> LOGSLICE) & 1023u);
        atomicAdd(&acc[pk[2] & (SLICE - 1)], (pk[2] >> LOGSLICE) & 1023u);
        atomicAdd(&acc[pk[3] & (SLICE - 1)], (pk[3] >> LOGSLICE) & 1023u);
    }
    for (uint32_t j = (n4 << 2) + t; j < rem; j += 1024) {
        uint32_t pk = p[j];
        atomicAdd(&acc[pk & (SLICE - 1)], (pk >> LOGSLICE) & 1023u);
    }
    __syncthreads();

    const int base4 = b * (SLICE / 4);
    for (int j = t; j < SLICE / 4; j += 1024) {
        v4i in = NTL(input4[base4 + j]);
        in[0] += (int)acc[j * 4 + 0];
        in[1] += (int)acc[j * 4 + 1];
        in[2] += (int)acc[j * 4 + 2];
        in[3] += (int)acc[j * 4 + 3];
        NTS(out4[base4 + j], in);
    }
}

// ---------- fallback: direct atomics ----------
__global__ void ip_copy_kernel(const int4* __restrict__ in, int4* __restrict__ out, int n4) {
    int stride = gridDim.x * blockDim.x;
    for (int i = blockIdx.x * blockDim.x + threadIdx.x; i < n4; i += stride)
        out[i] = in[i];
}
__global__ void ip_scatter1_kernel(const int* __restrict__ index, const int* __restrict__ value,
                                   int* __restrict__ out, int m) {
    int stride = gridDim.x * blockDim.x;
    for (int i = blockIdx.x * blockDim.x + threadIdx.x; i < m; i += stride)
        atomicAdd(&out[index[i]], value[i]);
}

extern "C" void kernel_launch(void* const* d_in, const int* in_sizes, int n_in,
                              void* d_out, int out_size, void* d_ws, size_t ws_size,
                              hipStream_t stream) {
    const int* input = (const int*)d_in[0];
    const int* index = (const int*)d_in[1];
    const int* value = (const int*)d_in[2];
    int* out = (int*)d_out;

    const int N = in_sizes[0];
    const int M = in_sizes[1];
    const int B = M / CHUNK;   // chunks (4096)

    const size_t gcnt_bytes = (size_t)B * NB * sizeof(uint32_t);      // 16 MB
    const size_t tot_bytes  = NB * sizeof(uint32_t);
    const size_t need = gcnt_bytes + 2 * tot_bytes + (size_t)M * sizeof(uint32_t);

    const bool ok = (N == NB * SLICE) && (M % CHUNK == 0) && (B == SC_THR * SC_EPT) &&
                    (B % 8 == 0) && (ws_size >= need);

    if (ok) {
        uint32_t* gcnt   = (uint32_t*)d_ws;
        uint32_t* btotal = (uint32_t*)((char*)d_ws + gcnt_bytes);
        uint32_t* bbase  = btotal + NB;
        uint32_t* pairs  = bbase + NB;

        ip_count<<<B, CNT_THR, 0, stream>>>((const v4u*)index, gcnt);
        ip_scan_chunks<<<NB, SC_THR, 0, stream>>>(gcnt, btotal);
        ip_scan_buckets<<<1, NB, 0, stream>>>(btotal, bbase);
        ip_bin<<<B, BIN_THR, 0, stream>>>((const v4u*)index, (const v4u*)value,
                                          gcnt, bbase, pairs);
        ip_accumulate<<<NB, 1024, 0, stream>>>(pairs, btotal, bbase,
                                               (const v4i*)input, (v4i*)out);
    } else {
        ip_copy_kernel<<<2048, 256, 0, stream>>>((const int4*)input, (int4*)d_out, N / 4);
        ip_scatter1_kernel<<<2048, 256, 0, stream>>>(index, value, out, M);
    }
}